// Round 11
// baseline (229.288 us; speedup 1.0000x reference)
//
#include <hip/hip_runtime.h>
#include <hip/hip_bf16.h>

#define HW    4096
#define CIN   256
#define COUT  256

// ws layout (float offsets):
// off_buf [294912]            @ 0
// wtb     bf16[2304][256]     @ 294912   (294912 float slots)
// outpre  [4][256][4096]      @ 589824   (4194304)
// bn      [512]               @ 4784128
// wob     bf16[288][32][8]    @ 4784640  (36864 float slots)  zero-padded 18->32 rows
// xt (NHWC f32 [4][4096][256]) lives in d_out, consumed before k_apply overwrites it.
#define WS_WTB  294912
#define WS_PRE  589824
#define WS_BN   4784128
#define WS_WOB  4784640

typedef __attribute__((ext_vector_type(8))) short bf16x8;
typedef __attribute__((ext_vector_type(4))) float f32x4;

__device__ inline ushort f2b(float v) {
    __hip_bfloat16 h = __float2bfloat16(v);
    return *reinterpret_cast<ushort*>(&h);
}

// pack w_conv[o][c][tap] (f32) -> wtb[k>>3][o][k&7] (bf16), k = c*9+tap
__global__ __launch_bounds__(256) void k_wtb(const float* __restrict__ wc,
                                             ushort* __restrict__ wtb) {
    int n = blockIdx.x;
#pragma unroll
    for (int i = 0; i < 9; ++i) {
        int k = i * 256 + threadIdx.x;
        float v = wc[n * 2304 + k];
        wtb[(k >> 3) * 2048 + n * 8 + (k & 7)] = f2b(v);
    }
}

// pack w_off[ch][c][tap] -> wob[k>>3][ch32][k&7] (bf16), rows 18..31 zero
__global__ __launch_bounds__(256) void k_wob(const float* __restrict__ w_off,
                                             ushort* __restrict__ wob) {
    int ch = blockIdx.x;                      // 0..31
#pragma unroll
    for (int i = 0; i < 9; ++i) {
        int k = i * 256 + threadIdx.x;
        float v = (ch < 18) ? w_off[ch * 2304 + k] : 0.f;
        wob[(k >> 3) * 256 + ch * 8 + (k & 7)] = f2b(v);
    }
}

// NCHW -> NHWC transpose: xt[b][hw][c] = x[b][c][hw]
__global__ __launch_bounds__(256) void k_xt(const float* __restrict__ x,
                                            float* __restrict__ xt) {
    __shared__ float tile[64][65];
    int blk = blockIdx.x;
    int b   = blk >> 8;
    int ct  = (blk >> 6) & 3;
    int hwt = blk & 63;
    int tid = threadIdx.x;
    const float* xb = x + ((size_t)(b * 256 + ct * 64)) * HW + hwt * 64;
#pragma unroll
    for (int p = 0; p < 16; ++p) {
        int c_l = p * 4 + (tid >> 6);
        int hw_l = tid & 63;
        tile[c_l][hw_l] = xb[(size_t)c_l * HW + hw_l];
    }
    __syncthreads();
    float* xo = xt + ((size_t)b * HW + hwt * 64) * 256 + ct * 64;
#pragma unroll
    for (int p = 0; p < 16; ++p) {
        int hw_l = p * 4 + (tid >> 6);
        int c_l = tid & 63;
        xo[(size_t)hw_l * 256 + c_l] = tile[c_l][hw_l];
    }
}

#define PAD_K 296   // 288 + 8 bf16 pad

// Offset conv as MFMA GEMM: off[18][pix] = W[18][2304] . im2col(x).
// 512 threads / 8 waves: 16 gather groups x 9 pairs; waves compute 2 frags
// redundantly; wave 0 stores (+bias).
__global__ __launch_bounds__(512, 8) void k_offmm(const float* __restrict__ xt,
                                                  const ushort* __restrict__ wob,
                                                  const float* __restrict__ b_off,
                                                  float* __restrict__ off_buf) {
    __shared__ ushort A_lds[16 * PAD_K];
    __shared__ int   m2_idx[144];
    __shared__ float m2_w[144];
    int mt = blockIdx.x;
    int b       = mt >> 8;
    int h       = (mt >> 2) & 63;
    int quarter = mt & 3;
    int tid = threadIdx.x;
    int l  = tid & 63;
    int wv = tid >> 6;                 // 0..7

    if (tid < 144) {
        int ppx = tid & 15, tap = tid >> 4;
        int imgc = quarter * 16 + ppx;
        int py  = h + tap / 3 - 1;
        int pxx = imgc + tap % 3 - 1;
        bool valid = (py >= 0 && py < 64 && pxx >= 0 && pxx < 64);
        m2_idx[tid] = min(max(py, 0), 63) * 64 + min(max(pxx, 0), 63);
        m2_w[tid] = valid ? 1.f : 0.f;
    }

    f32x4 acc2[2];
    acc2[0] = (f32x4){0.f, 0.f, 0.f, 0.f};
    acc2[1] = (f32x4){0.f, 0.f, 0.f, 0.f};

    const float* xtb = xt + (size_t)b * HW * 256;
    int cl = tid & 31;
    int p0 = tid >> 5;                 // 0..15

    for (int chunk = 0; chunk < 8; ++chunk) {
        int c0 = chunk * 32;
        __syncthreads();
        const float* bp = xtb + c0 + cl;
#pragma unroll
        for (int pp = 0; pp < 9; ++pp) {
            int pair = pp * 16 + p0;
            float v = m2_w[pair] * bp[m2_idx[pair] << 8];
            int ppx = pair & 15, tap = pair >> 4;
            A_lds[ppx * PAD_K + cl * 9 + tap] = f2b(v);
        }
        __syncthreads();
        int kg0 = chunk * 288;
        for (int st = 0; st < 9; ++st) {
            int kb = st * 32;
            int koff = kb + (l >> 4) * 8;
            bf16x8 smp = *(const bf16x8*)&A_lds[(l & 15) * PAD_K + koff];
            int ko = ((kg0 + kb) >> 3) + (l >> 4);
            const ushort* ap = wob + ko * 256 + (l & 15) * 8;
            bf16x8 w0 = *(const bf16x8*)(ap);
            bf16x8 w1 = *(const bf16x8*)(ap + 128);
            acc2[0] = __builtin_amdgcn_mfma_f32_16x16x32_bf16(w0, smp, acc2[0], 0, 0, 0);
            acc2[1] = __builtin_amdgcn_mfma_f32_16x16x32_bf16(w1, smp, acc2[1], 0, 0, 0);
        }
    }
    if (wv == 0) {
        int pixbase = (b * 64 + h) * 64 + quarter * 16 + (l & 15);
#pragma unroll
        for (int f = 0; f < 2; ++f)
#pragma unroll
            for (int r = 0; r < 4; ++r) {
                int ch = f * 16 + (l >> 4) * 4 + r;
                if (ch < 18) off_buf[pixbase * 18 + ch] = acc2[f][r] + b_off[ch];
            }
    }
}

// grid 1024, 512 threads / 8 waves: mt = b*256 + h*4 + quarter (16-px M-tile).
// Gather: 16 groups x 9 (px,tap) pairs, NHWC xt coalesced 128B per 32-lane group.
// MFMA: A = weights (rows=o), B = samples (cols=px) -> D[o][px]; wave owns 32 o.
__global__ __launch_bounds__(512, 8) void k_main(const float* __restrict__ xt,
                                                 const float* __restrict__ off_buf,
                                                 const ushort* __restrict__ wtb,
                                                 float* __restrict__ outpre) {
    __shared__ ushort A_lds[16 * PAD_K];
    __shared__ uint2  m_idx[144];
    __shared__ float4 m_w[144];
    int mt = blockIdx.x;
    int b       = mt >> 8;
    int h       = (mt >> 2) & 63;
    int quarter = mt & 3;
    int tid = threadIdx.x;
    int l  = tid & 63;
    int wv = tid >> 6;                 // 0..7 -> o base = wv*32

    if (tid < 144) {
        int ppx = tid & 15, tap = tid >> 4;
        int imgc = quarter * 16 + ppx;
        int pg = (b * 64 + h) * 64 + imgc;
        float offy = off_buf[pg * 18 + 2 * tap];
        float offx = off_buf[pg * 18 + 2 * tap + 1];
        float py  = (float)(h + tap / 3 - 1) + offy;
        float pxf = (float)(imgc + tap % 3 - 1) + offx;
        float fy0 = floorf(py), fx0 = floorf(pxf);
        int y0 = (int)fy0, x0 = (int)fx0;
        float fy = py - fy0, fx = pxf - fx0;
        float wy0 = (1.f - fy) * ((y0 >= 0 && y0 < 64) ? 1.f : 0.f);
        float wy1 = fy         * ((y0 >= -1 && y0 < 63) ? 1.f : 0.f);
        float wx0 = (1.f - fx) * ((x0 >= 0 && x0 < 64) ? 1.f : 0.f);
        float wx1 = fx         * ((x0 >= -1 && x0 < 63) ? 1.f : 0.f);
        int iy0 = min(max(y0, 0), 63) * 64;
        int iy1 = min(max(y0 + 1, 0), 63) * 64;
        int ix0 = min(max(x0, 0), 63);
        int ix1 = min(max(x0 + 1, 0), 63);
        m_idx[tid] = (uint2){ (uint)((iy0 + ix0) | ((iy0 + ix1) << 16)),
                              (uint)((iy1 + ix0) | ((iy1 + ix1) << 16)) };
        m_w[tid] = (float4){ wy0 * wx0, wy0 * wx1, wy1 * wx0, wy1 * wx1 };
    }

    f32x4 acc[2];
    acc[0] = (f32x4){0.f, 0.f, 0.f, 0.f};
    acc[1] = (f32x4){0.f, 0.f, 0.f, 0.f};

    const float* xtb = xt + (size_t)b * HW * 256;
    int cl = tid & 31;
    int p0 = tid >> 5;                 // 0..15

    for (int chunk = 0; chunk < 8; ++chunk) {
        int c0 = chunk * 32;
        __syncthreads();
        const float* bp = xtb + c0 + cl;
#pragma unroll
        for (int pp = 0; pp < 9; ++pp) {
            int pair = pp * 16 + p0;
            uint2 id = m_idx[pair];
            float4 w4 = m_w[pair];
            float v = w4.x * bp[(int)(id.x & 0xffffu) << 8]
                    + w4.y * bp[(int)(id.x >> 16) << 8]
                    + w4.z * bp[(int)(id.y & 0xffffu) << 8]
                    + w4.w * bp[(int)(id.y >> 16) << 8];
            int ppx = pair & 15, tap = pair >> 4;
            A_lds[ppx * PAD_K + cl * 9 + tap] = f2b(v);
        }
        __syncthreads();
        int kg0 = chunk * 288;
        for (int st = 0; st < 9; ++st) {
            int kb = st * 32;
            int koff = kb + (l >> 4) * 8;
            bf16x8 smp = *(const bf16x8*)&A_lds[(l & 15) * PAD_K + koff];
            int ko = ((kg0 + kb) >> 3) + (l >> 4);
            const ushort* ap = wtb + ko * 2048 + (wv * 32 + (l & 15)) * 8;
            bf16x8 w0 = *(const bf16x8*)(ap);
            bf16x8 w1 = *(const bf16x8*)(ap + 128);
            acc[0] = __builtin_amdgcn_mfma_f32_16x16x32_bf16(w0, smp, acc[0], 0, 0, 0);
            acc[1] = __builtin_amdgcn_mfma_f32_16x16x32_bf16(w1, smp, acc[1], 0, 0, 0);
        }
    }
    float* op = outpre + (size_t)(b * 256) * HW + h * 64 + quarter * 16;
#pragma unroll
    for (int f = 0; f < 2; ++f)
#pragma unroll
        for (int r = 0; r < 4; ++r) {
            int o = wv * 32 + f * 16 + (l >> 4) * 4 + r;
            op[o * HW + (l & 15)] = acc[f][r];
        }
}

__global__ __launch_bounds__(1024) void k_stats(const float* __restrict__ outpre,
                                                const float* __restrict__ gamma,
                                                const float* __restrict__ beta,
                                                float* __restrict__ bn) {
    int o = blockIdx.x;
    int tid = threadIdx.x;
    float s = 0.f, sq = 0.f;
    for (int f = tid; f < 16384; f += 1024) {
        int bb = f >> 12, hw = f & 4095;
        float v = outpre[((bb * 256 + o) << 12) + hw];
        s += v;
        sq += v * v;
    }
    __shared__ float rs[1024], rq[1024];
    rs[tid] = s; rq[tid] = sq;
    __syncthreads();
    for (int st = 512; st > 0; st >>= 1) {
        if (tid < st) { rs[tid] += rs[tid + st]; rq[tid] += rq[tid + st]; }
        __syncthreads();
    }
    if (tid == 0) {
        float mu = rs[0] * (1.f / 16384.f);
        float var = rq[0] * (1.f / 16384.f) - mu * mu;
        float sc = gamma[o] / sqrtf(var + 1e-5f);
        bn[o] = sc;
        bn[256 + o] = beta[o] - mu * sc;
    }
}

__global__ __launch_bounds__(256) void k_apply(const float* __restrict__ outpre,
                                               const float* __restrict__ bn,
                                               float* __restrict__ out) {
    int i4 = blockIdx.x * 256 + threadIdx.x;
    int o = (i4 >> 10) & 255;
    float sc = bn[o], sh = bn[256 + o];
    float4 v = ((const float4*)outpre)[i4];
    v.x = fmaxf(fmaf(v.x, sc, sh), 0.f);
    v.y = fmaxf(fmaf(v.y, sc, sh), 0.f);
    v.z = fmaxf(fmaf(v.z, sc, sh), 0.f);
    v.w = fmaxf(fmaf(v.w, sc, sh), 0.f);
    ((float4*)out)[i4] = v;
}

extern "C" void kernel_launch(void* const* d_in, const int* in_sizes, int n_in,
                              void* d_out, int out_size, void* d_ws, size_t ws_size,
                              hipStream_t stream) {
    const float* x      = (const float*)d_in[0];
    const float* w_off  = (const float*)d_in[1];
    const float* b_off  = (const float*)d_in[2];
    const float* w_conv = (const float*)d_in[3];
    const float* gamma  = (const float*)d_in[4];
    const float* beta   = (const float*)d_in[5];
    float* ws = (float*)d_ws;
    float* off_buf  = ws;
    ushort* wtb     = (ushort*)(ws + WS_WTB);
    float* outpre   = ws + WS_PRE;
    float* bn       = ws + WS_BN;
    ushort* wob     = (ushort*)(ws + WS_WOB);
    float* out = (float*)d_out;
    float* xt  = out;                       // d_out doubles as NHWC scratch

    hipLaunchKernelGGL(k_wtb,   dim3(256),  dim3(256), 0, stream, w_conv, wtb);
    hipLaunchKernelGGL(k_wob,   dim3(32),   dim3(256), 0, stream, w_off, wob);
    hipLaunchKernelGGL(k_xt,    dim3(1024), dim3(256), 0, stream, x, xt);
    hipLaunchKernelGGL(k_offmm, dim3(1024), dim3(512), 0, stream, xt, wob, b_off, off_buf);
    hipLaunchKernelGGL(k_main,  dim3(1024), dim3(512), 0, stream, xt, off_buf, wtb, outpre);
    hipLaunchKernelGGL(k_stats, dim3(256),  dim3(1024), 0, stream, outpre, gamma, beta, bn);
    hipLaunchKernelGGL(k_apply, dim3(4096), dim3(256), 0, stream, outpre, bn, out);
}

// Round 12
// 170.113 us; speedup vs baseline: 1.3479x; 1.3479x over previous
//
#include <hip/hip_runtime.h>
#include <hip/hip_bf16.h>

#define HW    4096
#define CIN   256
#define COUT  256

// ws layout (float offsets):
// off_buf [294912]            @ 0
// wtb     bf16[2304][256]     @ 294912   (tap-major K: k' = tap*256 + c)
// outpre  [4][256][4096]      @ 589824
// bn      [512]               @ 4784128
// wob     bf16[288oct][32][8] @ 4784640  (tap-major K, ch rows 18..31 zero)
// xt (NHWC bf16 [4][4096][256], 8.4 MB) lives in d_out, consumed before k_apply.
#define WS_WTB  294912
#define WS_PRE  589824
#define WS_BN   4784128
#define WS_WOB  4784640

typedef __attribute__((ext_vector_type(8))) short bf16x8;
typedef __attribute__((ext_vector_type(4))) float f32x4;

__device__ inline ushort f2b(float v) {
    __hip_bfloat16 h = __float2bfloat16(v);
    return *reinterpret_cast<ushort*>(&h);
}
__device__ inline float b2f(uint us) {
    union { uint u; float f; } cv; cv.u = (us & 0xffffu) << 16; return cv.f;
}

// pack w_conv[o][c][tap] -> wtb[k'>>3][o][k'&7], k' = tap*256 + c (tap-major)
__global__ __launch_bounds__(256) void k_wtb(const float* __restrict__ wc,
                                             ushort* __restrict__ wtb) {
    int n = blockIdx.x;
#pragma unroll
    for (int tap = 0; tap < 9; ++tap) {
        int c = threadIdx.x;
        int kp = tap * 256 + c;
        float v = wc[n * 2304 + c * 9 + tap];
        wtb[(kp >> 3) * 2048 + n * 8 + (kp & 7)] = f2b(v);
    }
}

// pack w_off[ch][c][tap] -> wob[k'>>3][ch32][k'&7], tap-major, rows 18..31 zero
__global__ __launch_bounds__(256) void k_wob(const float* __restrict__ w_off,
                                             ushort* __restrict__ wob) {
    int ch = blockIdx.x;                      // 0..31
#pragma unroll
    for (int tap = 0; tap < 9; ++tap) {
        int c = threadIdx.x;
        int kp = tap * 256 + c;
        float v = (ch < 18) ? w_off[ch * 2304 + c * 9 + tap] : 0.f;
        wob[(kp >> 3) * 256 + ch * 8 + (kp & 7)] = f2b(v);
    }
}

// NCHW f32 -> NHWC bf16: xt[b][hw][c]
__global__ __launch_bounds__(256) void k_xt(const float* __restrict__ x,
                                            ushort* __restrict__ xt) {
    __shared__ float tile[64][65];
    int blk = blockIdx.x;
    int b   = blk >> 8;
    int ct  = (blk >> 6) & 3;
    int hwt = blk & 63;
    int tid = threadIdx.x;
    const float* xb = x + ((size_t)(b * 256 + ct * 64)) * HW + hwt * 64;
#pragma unroll
    for (int p = 0; p < 16; ++p) {
        int c_l = p * 4 + (tid >> 6);
        int hw_l = tid & 63;
        tile[c_l][hw_l] = xb[(size_t)c_l * HW + hw_l];
    }
    __syncthreads();
    ushort* xo = xt + ((size_t)b * HW + hwt * 64) * 256 + ct * 64;
#pragma unroll
    for (int p = 0; p < 16; ++p) {
        int hw_l = p * 4 + (tid >> 6);
        int c_l = tid & 63;
        xo[(size_t)hw_l * 256 + c_l] = f2b(tile[c_l][hw_l]);
    }
}

#define PAD_K  296   // ushorts per A_lds row (288 + 8 pad)
#define PAD_KU 148   // uints per row

// Offset conv as MFMA GEMM, 32-px tile, bf16 xt (1 uint load = 2 channels/pair).
// 512 thr / 8 waves; wave wv: px-half mi=wv&1, 4x redundant in o; wv<2 stores.
__global__ __launch_bounds__(512, 4) void k_offmm(const ushort* __restrict__ xt,
                                                  const ushort* __restrict__ wob,
                                                  const float* __restrict__ b_off,
                                                  float* __restrict__ off_buf) {
    __shared__ ushort A_lds[32 * PAD_K];
    __shared__ int  m2_idx[288];
    __shared__ uint m2_m[288];
    int mt = blockIdx.x;                 // 0..511
    int b    = mt >> 7;
    int h    = (mt >> 1) & 63;
    int half = mt & 1;
    int tid = threadIdx.x;
    int l  = tid & 63;
    int wv = tid >> 6;

    if (tid < 288) {
        int ppx = tid & 31, tap = tid >> 5;
        int imgc = half * 32 + ppx;
        int py  = h + tap / 3 - 1;
        int pxx = imgc + tap % 3 - 1;
        bool valid = (py >= 0 && py < 64 && pxx >= 0 && pxx < 64);
        m2_idx[tid] = min(max(py, 0), 63) * 64 + min(max(pxx, 0), 63);
        m2_m[tid] = valid ? 0xffffffffu : 0u;
    }

    f32x4 acc2[2];
    acc2[0] = (f32x4){0.f, 0.f, 0.f, 0.f};
    acc2[1] = (f32x4){0.f, 0.f, 0.f, 0.f};

    const ushort* xtb = xt + (size_t)b * HW * 256;
    int cl = tid & 15;                   // 2-channel lane
    int p0 = tid >> 4;                   // pixel 0..31
    uint* Au = (uint*)A_lds;
    int mi = wv & 1;

    for (int chunk = 0; chunk < 8; ++chunk) {
        int c0 = chunk * 32;
        __syncthreads();
        const ushort* bp = xtb + c0 + cl * 2;
#pragma unroll
        for (int j = 0; j < 9; ++j) {
            int pair = j * 32 + p0;
            uint raw = *(const uint*)(bp + (m2_idx[pair] << 8));
            Au[p0 * PAD_KU + j * 16 + cl] = raw & m2_m[pair];
        }
        __syncthreads();
        for (int st = 0; st < 9; ++st) {
            const ushort* arow = &A_lds[((l & 15) + mi * 16) * PAD_K + st * 32 + (l >> 4) * 8];
            bf16x8 smp = *(const bf16x8*)arow;
            int ko = st * 32 + (c0 >> 3) + (l >> 4);
            const ushort* ap = wob + ko * 256 + (l & 15) * 8;
            bf16x8 w0 = *(const bf16x8*)(ap);
            bf16x8 w1 = *(const bf16x8*)(ap + 128);
            acc2[0] = __builtin_amdgcn_mfma_f32_16x16x32_bf16(w0, smp, acc2[0], 0, 0, 0);
            acc2[1] = __builtin_amdgcn_mfma_f32_16x16x32_bf16(w1, smp, acc2[1], 0, 0, 0);
        }
    }
    if (wv < 2) {                        // wv==0 -> px 0-15, wv==1 -> px 16-31
        int pixbase = (b * 64 + h) * 64 + half * 32 + wv * 16 + (l & 15);
#pragma unroll
        for (int f = 0; f < 2; ++f)
#pragma unroll
            for (int r = 0; r < 4; ++r) {
                int ch = f * 16 + (l >> 4) * 4 + r;
                if (ch < 18) off_buf[pixbase * 18 + ch] = acc2[f][r] + b_off[ch];
            }
    }
}

// Main einsum, 32-px tile, bf16 xt. grid 512, 512 thr / 8 waves.
// Wave wv owns o in [wv*32, wv*32+32); acc[mi][ni] covers 32px x 32o.
__global__ __launch_bounds__(512, 4) void k_main(const ushort* __restrict__ xt,
                                                 const float* __restrict__ off_buf,
                                                 const ushort* __restrict__ wtb,
                                                 float* __restrict__ outpre) {
    __shared__ ushort A_lds[32 * PAD_K];
    __shared__ uint2  m_idx[288];
    __shared__ float4 m_w[288];
    int mt = blockIdx.x;                 // 0..511
    int b    = mt >> 7;
    int h    = (mt >> 1) & 63;
    int half = mt & 1;
    int tid = threadIdx.x;
    int l  = tid & 63;
    int wv = tid >> 6;

    if (tid < 288) {
        int ppx = tid & 31, tap = tid >> 5;
        int imgc = half * 32 + ppx;
        int pg = (b * 64 + h) * 64 + imgc;
        float offy = off_buf[pg * 18 + 2 * tap];
        float offx = off_buf[pg * 18 + 2 * tap + 1];
        float py  = (float)(h + tap / 3 - 1) + offy;
        float pxf = (float)(imgc + tap % 3 - 1) + offx;
        float fy0 = floorf(py), fx0 = floorf(pxf);
        int y0 = (int)fy0, x0 = (int)fx0;
        float fy = py - fy0, fx = pxf - fx0;
        float wy0 = (1.f - fy) * ((y0 >= 0 && y0 < 64) ? 1.f : 0.f);
        float wy1 = fy         * ((y0 >= -1 && y0 < 63) ? 1.f : 0.f);
        float wx0 = (1.f - fx) * ((x0 >= 0 && x0 < 64) ? 1.f : 0.f);
        float wx1 = fx         * ((x0 >= -1 && x0 < 63) ? 1.f : 0.f);
        int iy0 = min(max(y0, 0), 63) * 64;
        int iy1 = min(max(y0 + 1, 0), 63) * 64;
        int ix0 = min(max(x0, 0), 63);
        int ix1 = min(max(x0 + 1, 0), 63);
        m_idx[tid] = (uint2){ (uint)((iy0 + ix0) | ((iy0 + ix1) << 16)),
                              (uint)((iy1 + ix0) | ((iy1 + ix1) << 16)) };
        m_w[tid] = (float4){ wy0 * wx0, wy0 * wx1, wy1 * wx0, wy1 * wx1 };
    }

    f32x4 acc[2][2];
#pragma unroll
    for (int mi = 0; mi < 2; ++mi)
#pragma unroll
        for (int ni = 0; ni < 2; ++ni)
            acc[mi][ni] = (f32x4){0.f, 0.f, 0.f, 0.f};

    const ushort* xtb = xt + (size_t)b * HW * 256;
    int cl = tid & 15;                   // 2-channel lane
    int p0 = tid >> 4;                   // pixel 0..31
    uint* Au = (uint*)A_lds;

    for (int chunk = 0; chunk < 8; ++chunk) {
        int c0 = chunk * 32;
        __syncthreads();
        const ushort* bp = xtb + c0 + cl * 2;
#pragma unroll
        for (int j = 0; j < 9; ++j) {
            int pair = j * 32 + p0;
            uint2 id = m_idx[pair];
            float4 w4 = m_w[pair];
            uint r00 = *(const uint*)(bp + ((id.x & 0xffffu) << 8));
            uint r01 = *(const uint*)(bp + ((id.x >> 16) << 8));
            uint r10 = *(const uint*)(bp + ((id.y & 0xffffu) << 8));
            uint r11 = *(const uint*)(bp + ((id.y >> 16) << 8));
            float lo = w4.x * b2f(r00) + w4.y * b2f(r01) +
                       w4.z * b2f(r10) + w4.w * b2f(r11);
            float hi = w4.x * b2f(r00 >> 16) + w4.y * b2f(r01 >> 16) +
                       w4.z * b2f(r10 >> 16) + w4.w * b2f(r11 >> 16);
            Au[p0 * PAD_KU + j * 16 + cl] = (uint)f2b(lo) | ((uint)f2b(hi) << 16);
        }
        __syncthreads();
        for (int st = 0; st < 9; ++st) {
            const ushort* arow = &A_lds[(l & 15) * PAD_K + st * 32 + (l >> 4) * 8];
            bf16x8 smp0 = *(const bf16x8*)arow;
            bf16x8 smp1 = *(const bf16x8*)(arow + 16 * PAD_K);
            int ko = st * 32 + (c0 >> 3) + (l >> 4);
            const ushort* ap = wtb + ko * 2048 + (wv * 32 + (l & 15)) * 8;
            bf16x8 w0 = *(const bf16x8*)(ap);
            bf16x8 w1 = *(const bf16x8*)(ap + 128);
            acc[0][0] = __builtin_amdgcn_mfma_f32_16x16x32_bf16(w0, smp0, acc[0][0], 0, 0, 0);
            acc[0][1] = __builtin_amdgcn_mfma_f32_16x16x32_bf16(w1, smp0, acc[0][1], 0, 0, 0);
            acc[1][0] = __builtin_amdgcn_mfma_f32_16x16x32_bf16(w0, smp1, acc[1][0], 0, 0, 0);
            acc[1][1] = __builtin_amdgcn_mfma_f32_16x16x32_bf16(w1, smp1, acc[1][1], 0, 0, 0);
        }
    }
    // D[o][px]: row=(l>>4)*4+r -> o, col=l&15 -> px (within mi half)
    float* op = outpre + (size_t)(b * 256) * HW + h * 64 + half * 32;
#pragma unroll
    for (int mi = 0; mi < 2; ++mi)
#pragma unroll
        for (int ni = 0; ni < 2; ++ni)
#pragma unroll
            for (int r = 0; r < 4; ++r) {
                int o = wv * 32 + ni * 16 + (l >> 4) * 4 + r;
                op[o * HW + mi * 16 + (l & 15)] = acc[mi][ni][r];
            }
}

__global__ __launch_bounds__(1024) void k_stats(const float* __restrict__ outpre,
                                                const float* __restrict__ gamma,
                                                const float* __restrict__ beta,
                                                float* __restrict__ bn) {
    int o = blockIdx.x;
    int tid = threadIdx.x;
    float s = 0.f, sq = 0.f;
    for (int f = tid; f < 16384; f += 1024) {
        int bb = f >> 12, hw = f & 4095;
        float v = outpre[((bb * 256 + o) << 12) + hw];
        s += v;
        sq += v * v;
    }
    __shared__ float rs[1024], rq[1024];
    rs[tid] = s; rq[tid] = sq;
    __syncthreads();
    for (int st = 512; st > 0; st >>= 1) {
        if (tid < st) { rs[tid] += rs[tid + st]; rq[tid] += rq[tid + st]; }
        __syncthreads();
    }
    if (tid == 0) {
        float mu = rs[0] * (1.f / 16384.f);
        float var = rq[0] * (1.f / 16384.f) - mu * mu;
        float sc = gamma[o] / sqrtf(var + 1e-5f);
        bn[o] = sc;
        bn[256 + o] = beta[o] - mu * sc;
    }
}

__global__ __launch_bounds__(256) void k_apply(const float* __restrict__ outpre,
                                               const float* __restrict__ bn,
                                               float* __restrict__ out) {
    int i4 = blockIdx.x * 256 + threadIdx.x;
    int o = (i4 >> 10) & 255;
    float sc = bn[o], sh = bn[256 + o];
    float4 v = ((const float4*)outpre)[i4];
    v.x = fmaxf(fmaf(v.x, sc, sh), 0.f);
    v.y = fmaxf(fmaf(v.y, sc, sh), 0.f);
    v.z = fmaxf(fmaf(v.z, sc, sh), 0.f);
    v.w = fmaxf(fmaf(v.w, sc, sh), 0.f);
    ((float4*)out)[i4] = v;
}

extern "C" void kernel_launch(void* const* d_in, const int* in_sizes, int n_in,
                              void* d_out, int out_size, void* d_ws, size_t ws_size,
                              hipStream_t stream) {
    const float* x      = (const float*)d_in[0];
    const float* w_off  = (const float*)d_in[1];
    const float* b_off  = (const float*)d_in[2];
    const float* w_conv = (const float*)d_in[3];
    const float* gamma  = (const float*)d_in[4];
    const float* beta   = (const float*)d_in[5];
    float* ws = (float*)d_ws;
    float* off_buf  = ws;
    ushort* wtb     = (ushort*)(ws + WS_WTB);
    float* outpre   = ws + WS_PRE;
    float* bn       = ws + WS_BN;
    ushort* wob     = (ushort*)(ws + WS_WOB);
    float* out = (float*)d_out;
    ushort* xt = (ushort*)d_out;            // bf16 NHWC scratch in d_out (8.4 MB),
                                            // consumed before k_apply overwrites d_out

    hipLaunchKernelGGL(k_wtb,   dim3(256),  dim3(256), 0, stream, w_conv, wtb);
    hipLaunchKernelGGL(k_wob,   dim3(32),   dim3(256), 0, stream, w_off, wob);
    hipLaunchKernelGGL(k_xt,    dim3(1024), dim3(256), 0, stream, x, xt);
    hipLaunchKernelGGL(k_offmm, dim3(512),  dim3(512), 0, stream, xt, wob, b_off, off_buf);
    hipLaunchKernelGGL(k_main,  dim3(512),  dim3(512), 0, stream, xt, off_buf, wtb, outpre);
    hipLaunchKernelGGL(k_stats, dim3(256),  dim3(1024), 0, stream, outpre, gamma, beta, bn);
    hipLaunchKernelGGL(k_apply, dim3(4096), dim3(256), 0, stream, outpre, bn, out);
}